// Round 2
// baseline (497.797 us; speedup 1.0000x reference)
//
#include <hip/hip_runtime.h>
#include <cstdint>
#include <cstddef>

// B=1024 tokens, D=1024, E=16 experts, H=2048, O=1024, top-4 routing.
typedef __bf16 bh;
typedef bh bh8 __attribute__((ext_vector_type(8)));
typedef bh bh4 __attribute__((ext_vector_type(4)));
typedef float fx4 __attribute__((ext_vector_type(4)));

__device__ __forceinline__ void gload16(const void* g, void* l) {
  // async global->LDS, 16B/lane; LDS dest is wave-uniform base + lane*16
  __builtin_amdgcn_global_load_lds(
      (const __attribute__((address_space(1))) void*)g,
      (__attribute__((address_space(3))) void*)l, 16, 0, 0);
}

// XOR swizzle: chunk c of LDS row r lives in slot c ^ swz(r).
// Spreads both manual ds_write_b128 (row&1 const per instr) and the
// frag reads across all 8 four-bank groups -> conflict-free.
__device__ __forceinline__ int swz(int r) { return (r >> 1) & 3; }

// ---------------- gating: one block per token ----------------
__global__ __launch_bounds__(256) void k_gating(
    const float* __restrict__ x, const float* __restrict__ wg,
    const float* __restrict__ wn, const float* __restrict__ nz,
    bh* __restrict__ xbf, unsigned* __restrict__ cnt,
    int* __restrict__ tok_buck, float* __restrict__ gate_buck,
    float* __restrict__ imp_part, float* __restrict__ load_part) {
  const int b = blockIdx.x, tid = threadIdx.x;
  __shared__ __align__(16) float xs[1024];
  __shared__ float part[32][9];
  __shared__ float vals[32];
  fx4 v = *(const fx4*)(x + (size_t)b * 1024 + tid * 4);
  *(fx4*)(xs + tid * 4) = v;
  bh4 xb;
#pragma unroll
  for (int u = 0; u < 4; ++u) xb[u] = (bh)v[u];
  *(bh4*)(xbf + (size_t)b * 1024 + tid * 4) = xb;
  __syncthreads();
  const int col = tid & 31, g = tid >> 5;
  const float* wp = ((col < 16) ? wg : wn) + (col & 15);
  float s = 0.f;
  for (int it = g * 128; it < g * 128 + 128; ++it) s += xs[it] * wp[it * 16];
  part[col][g] = s;
  __syncthreads();
  if (tid < 32) {
    float tsum = 0.f;
#pragma unroll
    for (int gg = 0; gg < 8; ++gg) tsum += part[tid][gg];
    vals[tid] = tsum;
  }
  __syncthreads();
  if (tid == 0) {
    float clean[16], sd[16], noisy[16];
#pragma unroll
    for (int e = 0; e < 16; ++e) {
      clean[e] = vals[e];
      float raw = vals[16 + e];
      float sp = fmaxf(raw, 0.f) + log1pf(expf(-fabsf(raw)));
      sd[e] = sp + 0.1f;
      noisy[e] = clean[e] + nz[b * 16 + e] * sd[e];
    }
    float tv[5]; int ti[5]; unsigned used = 0;
    for (int r = 0; r < 5; ++r) {
      float bst = -INFINITY; int bi = 0;
      for (int e = 0; e < 16; ++e)
        if (!((used >> e) & 1u) && noisy[e] > bst) { bst = noisy[e]; bi = e; }
      used |= 1u << bi; tv[r] = bst; ti[r] = bi;
    }
    float gts[4]; float se = 0.f;
#pragma unroll
    for (int k = 0; k < 4; ++k) { gts[k] = expf(tv[k] - tv[0]); se += gts[k]; }
#pragma unroll
    for (int k = 0; k < 4; ++k) gts[k] /= se;
    const float thr_in = tv[4], thr_out = tv[3];
    float imp[16];
#pragma unroll
    for (int e = 0; e < 16; ++e) imp[e] = 0.f;
    for (int k = 0; k < 4; ++k) imp[ti[k]] = gts[k];
    for (int e = 0; e < 16; ++e) imp_part[b * 16 + e] = imp[e];
    for (int e = 0; e < 16; ++e) {
      bool is_in = noisy[e] > thr_in;
      float z = (clean[e] - (is_in ? thr_in : thr_out)) / sd[e];
      load_part[b * 16 + e] = 0.5f * (1.f + erff(z * 0.70710678118654752f));
    }
    for (int k = 0; k < 4; ++k) {
      int ee = ti[k];
      unsigned p = atomicAdd(&cnt[ee], 1u);
      tok_buck[ee * 1024 + (int)p] = b;
      gate_buck[ee * 1024 + (int)p] = gts[k];
    }
  }
}

__device__ __forceinline__ float cv2_16(const float* v) {
  float m = 0.f;
  for (int i = 0; i < 16; ++i) m += v[i];
  m *= (1.f / 16.f);
  float var = 0.f;
  for (int i = 0; i < 16; ++i) { float d = v[i] - m; var += d * d; }
  var *= (1.f / 15.f);
  return var / (m * m + 1e-10f);
}

// ---------------- offsets + loss ----------------
__global__ __launch_bounds__(256) void k_finalize(
    const unsigned* __restrict__ cnt, unsigned* __restrict__ offs,
    const float* __restrict__ imp_part, const float* __restrict__ load_part,
    float* __restrict__ loss_out) {
  const int tid = threadIdx.x;
  __shared__ float red[256];
  __shared__ float impv[16], loadv[16];
  const int e = tid & 15, p = tid >> 4;
  float s = 0.f;
  for (int r = 0; r < 64; ++r) s += imp_part[((p * 64 + r) << 4) + e];
  red[tid] = s;
  __syncthreads();
  if (tid < 16) {
    float t = 0.f;
    for (int pp = 0; pp < 16; ++pp) t += red[pp * 16 + tid];
    impv[tid] = t;
  }
  __syncthreads();
  s = 0.f;
  for (int r = 0; r < 64; ++r) s += load_part[((p * 64 + r) << 4) + e];
  red[tid] = s;
  __syncthreads();
  if (tid < 16) {
    float t = 0.f;
    for (int pp = 0; pp < 16; ++pp) t += red[pp * 16 + tid];
    loadv[tid] = t;
  }
  __syncthreads();
  if (tid == 0) {
    unsigned o = 0;
    for (int ee = 0; ee < 16; ++ee) { offs[ee] = o; o += cnt[ee]; }
    loss_out[0] = (cv2_16(impv) + cv2_16(loadv)) * 1e-4f;
  }
}

// ---------------- GEMM1 fused: h = relu(x @ W1[e] + b1[e]) ----------------
// A: gathered bf16 x rows, M-tile 256 (2x128 acc chunks) -> W1 streamed once.
// B: fp32 W1[e][k][n] transposed+converted to bf16 on the fly into LDS.
__global__ __launch_bounds__(256, 2) void k_gemm1f(
    const bh* __restrict__ xbf, const float* __restrict__ W1,
    const float* __restrict__ b1, const int* __restrict__ tok_buck,
    const unsigned* __restrict__ cnt, const unsigned* __restrict__ offs,
    bh* __restrict__ hbf) {
  const int e = blockIdx.z, mt = blockIdx.y, nt = blockIdx.x;
  const int ne = (int)cnt[e];
  if (mt * 256 >= ne) return;
  __shared__ __align__(16) bh As[256 * 32];  // 16 KB
  __shared__ __align__(16) bh Bs[128 * 32];  // 8 KB
  const int tid = threadIdx.x;
  const int lane = tid & 63, wv = tid >> 6, wm = wv >> 1, wn_ = wv & 1;

  // A gather (4 gload rounds of 4 KB)
  const bh* a_src[4]; void* a_dst[4];
#pragma unroll
  for (int r = 0; r < 4; ++r) {
    int task = r * 256 + tid;
    int row = task >> 2, s = task & 3;
    int gm = mt * 256 + row; if (gm >= ne) gm = ne - 1;
    int tok = tok_buck[e * 1024 + gm];
    a_src[r] = xbf + (size_t)tok * 1024 + ((s ^ swz(row)) << 3);
    a_dst[r] = (char*)As + (size_t)(r * 256 + (wv << 6)) * 16;
  }
  // B source: thread covers n = nt*128 + (tid&127), k = kt*32 + khalf*16 + i
  const int nl = tid & 127, khalf = tid >> 7;
  const float* bp = W1 + (size_t)e * (1024 * 2048) +
                    (size_t)(khalf * 16) * 2048 + nt * 128 + nl;
  bh8* wp0 = (bh8*)(Bs + nl * 32 + (((khalf * 2)     ^ swz(nl)) << 3));
  bh8* wp1 = (bh8*)(Bs + nl * 32 + (((khalf * 2 + 1) ^ swz(nl)) << 3));

  const int ln15 = lane & 15, q = lane >> 4;
  const int qs = (q ^ swz(ln15)) << 3;
  int a_off[2][4], b_off[4];
#pragma unroll
  for (int c = 0; c < 2; ++c)
#pragma unroll
    for (int i = 0; i < 4; ++i)
      a_off[c][i] = (c * 128 + wm * 64 + i * 16 + ln15) * 32 + qs;
#pragma unroll
  for (int j = 0; j < 4; ++j) b_off[j] = (wn_ * 64 + j * 16 + ln15) * 32 + qs;

  fx4 zero = {0.f, 0.f, 0.f, 0.f};
  fx4 acc[2][4][4];
#pragma unroll
  for (int c = 0; c < 2; ++c)
#pragma unroll
    for (int i = 0; i < 4; ++i)
#pragma unroll
      for (int j = 0; j < 4; ++j) acc[c][i][j] = zero;

  for (int kt = 0; kt < 32; ++kt) {
    __syncthreads();
    const int ko = kt * 32;
    float bv[16];
#pragma unroll
    for (int i = 0; i < 16; ++i) bv[i] = bp[(size_t)(ko + i) * 2048];
#pragma unroll
    for (int r = 0; r < 4; ++r) gload16(a_src[r] + ko, a_dst[r]);
    bh8 lo, hi;
#pragma unroll
    for (int u = 0; u < 8; ++u) { lo[u] = (bh)bv[u]; hi[u] = (bh)bv[8 + u]; }
    *wp0 = lo; *wp1 = hi;
    __syncthreads();
    bh8 bfr[4];
#pragma unroll
    for (int j = 0; j < 4; ++j) bfr[j] = *(const bh8*)(Bs + b_off[j]);
#pragma unroll
    for (int c = 0; c < 2; ++c) {
      bh8 af[4];
#pragma unroll
      for (int i = 0; i < 4; ++i) af[i] = *(const bh8*)(As + a_off[c][i]);
#pragma unroll
      for (int i = 0; i < 4; ++i)
#pragma unroll
        for (int j = 0; j < 4; ++j)
          acc[c][i][j] = __builtin_amdgcn_mfma_f32_16x16x32_bf16(af[i], bfr[j], acc[c][i][j], 0, 0, 0);
    }
  }

  int nrows = ne - mt * 256; if (nrows > 256) nrows = 256;
  int jn[4]; float b1v[4];
#pragma unroll
  for (int j = 0; j < 4; ++j) {
    jn[j] = nt * 128 + wn_ * 64 + j * 16 + ln15;
    b1v[j] = b1[e * 2048 + jn[j]];
  }
  const int rowbase = (int)offs[e] + mt * 256;
#pragma unroll
  for (int c = 0; c < 2; ++c)
#pragma unroll
    for (int i = 0; i < 4; ++i)
#pragma unroll
      for (int rr = 0; rr < 4; ++rr) {
        int ml = c * 128 + wm * 64 + i * 16 + q * 4 + rr;
        if (ml < nrows) {
          size_t ro = (size_t)(rowbase + ml) * 2048;
#pragma unroll
          for (int j = 0; j < 4; ++j) {
            float vv = acc[c][i][j][rr] + b1v[j];
            hbf[ro + jn[j]] = (bh)fmaxf(vv, 0.f);
          }
        }
      }
}

// ---------------- GEMM2 fused: y += gate * exp(h @ W2[e] + b2[e]) ----------------
__global__ __launch_bounds__(256, 2) void k_gemm2f(
    const bh* __restrict__ hbf, const float* __restrict__ W2,
    const float* __restrict__ b2, const int* __restrict__ tok_buck,
    const float* __restrict__ gate_buck, const unsigned* __restrict__ cnt,
    const unsigned* __restrict__ offs, float* __restrict__ yv) {
  const int e = blockIdx.z, mt = blockIdx.y, nt = blockIdx.x;
  const int ne = (int)cnt[e];
  if (mt * 256 >= ne) return;
  __shared__ __align__(16) bh As[256 * 32];
  __shared__ __align__(16) bh Bs[128 * 32];
  const int tid = threadIdx.x;
  const int lane = tid & 63, wv = tid >> 6, wm = wv >> 1, wn_ = wv & 1;
  int nrows = ne - mt * 256; if (nrows > 256) nrows = 256;
  const int rowbase = (int)offs[e] + mt * 256;

  const bh* a_src[4]; void* a_dst[4];
#pragma unroll
  for (int r = 0; r < 4; ++r) {
    int task = r * 256 + tid;
    int row = task >> 2, s = task & 3;
    int gr = row; if (gr >= nrows) gr = nrows - 1;
    a_src[r] = hbf + (size_t)(rowbase + gr) * 2048 + ((s ^ swz(row)) << 3);
    a_dst[r] = (char*)As + (size_t)(r * 256 + (wv << 6)) * 16;
  }
  const int nl = tid & 127, khalf = tid >> 7;
  const float* bp = W2 + (size_t)e * (2048 * 1024) +
                    (size_t)(khalf * 16) * 1024 + nt * 128 + nl;
  bh8* wp0 = (bh8*)(Bs + nl * 32 + (((khalf * 2)     ^ swz(nl)) << 3));
  bh8* wp1 = (bh8*)(Bs + nl * 32 + (((khalf * 2 + 1) ^ swz(nl)) << 3));

  const int ln15 = lane & 15, q = lane >> 4;
  const int qs = (q ^ swz(ln15)) << 3;
  int a_off[2][4], b_off[4];
#pragma unroll
  for (int c = 0; c < 2; ++c)
#pragma unroll
    for (int i = 0; i < 4; ++i)
      a_off[c][i] = (c * 128 + wm * 64 + i * 16 + ln15) * 32 + qs;
#pragma unroll
  for (int j = 0; j < 4; ++j) b_off[j] = (wn_ * 64 + j * 16 + ln15) * 32 + qs;

  fx4 zero = {0.f, 0.f, 0.f, 0.f};
  fx4 acc[2][4][4];
#pragma unroll
  for (int c = 0; c < 2; ++c)
#pragma unroll
    for (int i = 0; i < 4; ++i)
#pragma unroll
      for (int j = 0; j < 4; ++j) acc[c][i][j] = zero;

  for (int kt = 0; kt < 64; ++kt) {
    __syncthreads();
    const int ko = kt * 32;
    float bv[16];
#pragma unroll
    for (int i = 0; i < 16; ++i) bv[i] = bp[(size_t)(ko + i) * 1024];
#pragma unroll
    for (int r = 0; r < 4; ++r) gload16(a_src[r] + ko, a_dst[r]);
    bh8 lo, hi;
#pragma unroll
    for (int u = 0; u < 8; ++u) { lo[u] = (bh)bv[u]; hi[u] = (bh)bv[8 + u]; }
    *wp0 = lo; *wp1 = hi;
    __syncthreads();
    bh8 bfr[4];
#pragma unroll
    for (int j = 0; j < 4; ++j) bfr[j] = *(const bh8*)(Bs + b_off[j]);
#pragma unroll
    for (int c = 0; c < 2; ++c) {
      bh8 af[4];
#pragma unroll
      for (int i = 0; i < 4; ++i) af[i] = *(const bh8*)(As + a_off[c][i]);
#pragma unroll
      for (int i = 0; i < 4; ++i)
#pragma unroll
        for (int j = 0; j < 4; ++j)
          acc[c][i][j] = __builtin_amdgcn_mfma_f32_16x16x32_bf16(af[i], bfr[j], acc[c][i][j], 0, 0, 0);
    }
  }

  int on[4]; float b2v[4];
#pragma unroll
  for (int j = 0; j < 4; ++j) {
    on[j] = nt * 128 + wn_ * 64 + j * 16 + ln15;
    b2v[j] = b2[e * 1024 + on[j]];
  }
#pragma unroll
  for (int c = 0; c < 2; ++c)
#pragma unroll
    for (int i = 0; i < 4; ++i)
#pragma unroll
      for (int rr = 0; rr < 4; ++rr) {
        int ml = c * 128 + wm * 64 + i * 16 + q * 4 + rr;
        if (ml < nrows) {
          int pos = mt * 256 + ml;
          int bt = tok_buck[e * 1024 + pos];
          float gg = gate_buck[e * 1024 + pos];
          float* yrow = yv + (size_t)bt * 1024;
#pragma unroll
          for (int j = 0; j < 4; ++j)
            atomicAdd(&yrow[on[j]], gg * expf(acc[c][i][j][rr] + b2v[j]));
        }
      }
}

// ---------------- final log ----------------
__global__ __launch_bounds__(256) void k_log(float* __restrict__ yv) {
  const int i = blockIdx.x * 256 + threadIdx.x;
  fx4* p = (fx4*)yv + i;
  fx4 v = *p;
#pragma unroll
  for (int c = 0; c < 4; ++c) {
    float w = v[c];
    if (w == 0.f) w = 2.2204460492503131e-16f;
    v[c] = logf(w);
  }
  *p = v;
}

extern "C" void kernel_launch(void* const* d_in, const int* in_sizes, int n_in,
                              void* d_out, int out_size, void* d_ws, size_t ws_size,
                              hipStream_t stream) {
  const float* x  = (const float*)d_in[0];
  const float* wg = (const float*)d_in[1];
  const float* wn = (const float*)d_in[2];
  const float* W1 = (const float*)d_in[3];
  const float* b1 = (const float*)d_in[4];
  const float* W2 = (const float*)d_in[5];
  const float* b2 = (const float*)d_in[6];
  const float* nz = (const float*)d_in[7];
  float* out = (float*)d_out;

  char* ws = (char*)d_ws;
  unsigned* cnt      = (unsigned*)(ws + 0);            // 64 B
  unsigned* offs     = (unsigned*)(ws + 64);           // 64 B
  float*    imp_part = (float*)(ws + 256);             // 64 KB
  float*    load_part= (float*)(ws + 256 + 65536);     // 64 KB
  int*      tok_buck = (int*)(ws + 256 + 2 * 65536);   // 64 KB
  float*    gate_buck= (float*)(ws + 256 + 3 * 65536); // 64 KB
  bh*       xbf      = (bh*)(ws + 262400);             // 2 MiB
  bh*       hbf      = (bh*)(ws + 2359552);            // 4096*2048*2 = 16 MiB
  const size_t needed = 2359552 + (size_t)4096 * 2048 * 2;
  if (ws_size < needed) {
    hipMemsetAsync(d_out, 0x42, (size_t)out_size * 4, stream);  // sentinel
    return;
  }

  hipMemsetAsync(d_out, 0, (size_t)out_size * 4, stream);
  hipMemsetAsync(cnt, 0, 64, stream);

  k_gating<<<1024, 256, 0, stream>>>(x, wg, wn, nz, xbf, cnt, tok_buck, gate_buck,
                                     imp_part, load_part);
  k_finalize<<<1, 256, 0, stream>>>(cnt, offs, imp_part, load_part, out + (out_size - 1));
  k_gemm1f<<<dim3(16, 4, 16), 256, 0, stream>>>(xbf, W1, b1, tok_buck, cnt, offs, hbf);
  k_gemm2f<<<dim3(8, 4, 16), 256, 0, stream>>>(hbf, W2, b2, tok_buck, gate_buck, cnt, offs, out);
  k_log<<<1024, 256, 0, stream>>>(out);
}